// Round 23
// baseline (1812.519 us; speedup 1.0000x reference)
//
#include <hip/hip_runtime.h>
#include <math.h>

#define BB 4
#define NN 8192
#define DD 256
#define KK 512
#define NITERS 10

#define TAU 0.06f     // 2-term margin below which we re-rank in f64

typedef _Float16 f16;
typedef f16   f16x8 __attribute__((ext_vector_type(8)));
typedef float f32x4 __attribute__((ext_vector_type(4)));

// ---------------- init: centers0 = x[:, :K, :]  (f32 + f16 hi + c2) --------
__global__ __launch_bounds__(256) void init_centers_k(const float* __restrict__ x,
                                                      float* __restrict__ centers,
                                                      f16* __restrict__ chh,
                                                      float* __restrict__ c2) {
    __shared__ float sq[256];
    int bk = blockIdx.x;
    int b  = bk >> 9;
    int k  = bk & 511;
    int t  = threadIdx.x;
    size_t idx = (size_t)bk * DD + t;
    float v = x[((size_t)b * NN + k) * DD + t];
    centers[idx] = v;
    chh[idx] = (f16)v;
    sq[t] = v * v;
    __syncthreads();
    for (int s = 128; s > 0; s >>= 1) {
        if (t < s) sq[t] += sq[t + s];
        __syncthreads();
    }
    if (t == 0) c2[bk] = sq[0];
}

// ---------------- x -> f16 hi/lo mirrors (once; x is constant) -------------
__global__ __launch_bounds__(256) void xsplit_k(const float* __restrict__ x,
                                                f16* __restrict__ xh,
                                                f16* __restrict__ xl) {
    size_t i = ((size_t)blockIdx.x * 256 + threadIdx.x) * 8;
    float4 a  = *(const float4*)(x + i);
    float4 bq = *(const float4*)(x + i + 4);
    float vf[8] = {a.x, a.y, a.z, a.w, bq.x, bq.y, bq.z, bq.w};
    f16x8 hv, lv;
    #pragma unroll
    for (int j = 0; j < 8; ++j) {
        f16 h = (f16)vf[j];
        hv[j] = h;
        lv[j] = (f16)(vf[j] - (float)h);
    }
    *(f16x8*)(xh + i) = hv;
    *(f16x8*)(xl + i) = lv;
}

// ---------------- row sum of squares for x (once per call) -----------------
__global__ __launch_bounds__(256) void rowsumsq_k(const float* __restrict__ rows,
                                                  float* __restrict__ out, int nrows) {
    int r = blockIdx.x * 256 + threadIdx.x;
    if (r >= nrows) return;
    const float* p = rows + (size_t)r * DD;
    float total = 0.f;
    #pragma unroll
    for (int h = 0; h < 2; ++h) {
        float a[8];
        #pragma unroll
        for (int j = 0; j < 8; ++j) a[j] = 0.f;
        for (int i = 0; i < 128; i += 8) {
            #pragma unroll
            for (int j = 0; j < 8; ++j) {
                float v  = p[h * 128 + i + j];
                float sq = __fmul_rn(v, v);
                a[j] = __fadd_rn(a[j], sq);
            }
        }
        float s = __fadd_rn(__fadd_rn(__fadd_rn(a[0], a[1]), __fadd_rn(a[2], a[3])),
                            __fadd_rn(__fadd_rn(a[4], a[5]), __fadd_rn(a[6], a[7])));
        total = __fadd_rn(total, s);
    }
    out[r] = total;
}

// ---------------- 2-term split-f16 MFMA distance (R17 shape) ---------------
__global__ __launch_bounds__(256, 2) void assign_k(
    const f16* __restrict__ xh, const f16* __restrict__ xl,
    const f16* __restrict__ chh,
    const float* __restrict__ x2g, const float* __restrict__ c2g,
    int* __restrict__ labels, int* __restrict__ flagslot, int* __restrict__ flaglist)
{
    __shared__ f16 xlh[64 * 256];
    __shared__ f16 xll[64 * 256];
    __shared__ float rv1s[4][64];
    __shared__ float rv2s[4][64];
    __shared__ int   rk1s[4][64];

    const int tid  = threadIdx.x;
    const int wid  = tid >> 6;
    const int lane = tid & 63;
    const int l15  = lane & 15;
    const int lg   = lane >> 4;          // 0..3
    const int b    = blockIdx.x >> 7;    // 128 blocks per batch
    const int m0   = (blockIdx.x & 127) * 64;

    const f16* xhb = xh + (size_t)(b * NN + m0) * DD;
    const f16* xlb = xl + (size_t)(b * NN + m0) * DD;

    // stage x tile (64 x 256) from f16 mirrors, swizzled granules
    #pragma unroll
    for (int i = 0; i < 8; ++i) {
        int lin = tid + i * 256;          // 0..2047
        int row = lin >> 5, g = lin & 31;
        size_t goff = (size_t)row * DD + g * 8;
        f16x8 hv = *(const f16x8*)(xhb + goff);
        f16x8 lv = *(const f16x8*)(xlb + goff);
        int si = row * 256 + ((g ^ (row & 7)) << 3);
        *(f16x8*)&xlh[si] = hv;
        *(f16x8*)&xll[si] = lv;
    }
    __syncthreads();

    const f16* bhb = chh + ((size_t)b * KK + wid * 128) * DD;

    f32x4 acc[4][8];
    #pragma unroll
    for (int mi = 0; mi < 4; ++mi)
        #pragma unroll
        for (int ki = 0; ki < 8; ++ki)
            acc[mi][ki] = (f32x4){0.f, 0.f, 0.f, 0.f};

    #pragma unroll
    for (int s = 0; s < 8; ++s) {
        const int d0 = s * 32;
        f16x8 bh[8];
        #pragma unroll
        for (int ki = 0; ki < 8; ++ki) {
            size_t off = (size_t)(ki * 16 + l15) * DD + d0 + lg * 8;
            bh[ki] = *(const f16x8*)(bhb + off);
        }
        f16x8 ah[4], al[4];
        #pragma unroll
        for (int mi = 0; mi < 4; ++mi) {
            int row = mi * 16 + l15;
            int g   = (d0 >> 3) + lg;
            int si  = row * 256 + ((g ^ (row & 7)) << 3);
            ah[mi] = *(const f16x8*)&xlh[si];
            al[mi] = *(const f16x8*)&xll[si];
        }
        #pragma unroll
        for (int ki = 0; ki < 8; ++ki) {
            #pragma unroll
            for (int mi = 0; mi < 4; ++mi) {
                acc[mi][ki] = __builtin_amdgcn_mfma_f32_16x16x32_f16(ah[mi], bh[ki], acc[mi][ki], 0, 0, 0);
                acc[mi][ki] = __builtin_amdgcn_mfma_f32_16x16x32_f16(al[mi], bh[ki], acc[mi][ki], 0, 0, 0);
            }
        }
    }

    // epilogue: candidates + top-2 (point = mi*16+lg*4+r, col = wid*128+ki*16+l15)
    float c2v[8];
    #pragma unroll
    for (int ki = 0; ki < 8; ++ki)
        c2v[ki] = c2g[b * KK + wid * 128 + ki * 16 + l15];

    #pragma unroll
    for (int mi = 0; mi < 4; ++mi) {
        #pragma unroll
        for (int r = 0; r < 4; ++r) {
            int p = mi * 16 + lg * 4 + r;
            float x2p = x2g[b * NN + m0 + p];
            float v1 = __builtin_inff(), v2 = __builtin_inff();
            int   k1 = 0x7fffffff;
            #pragma unroll
            for (int ki = 0; ki < 8; ++ki) {
                float s    = acc[mi][ki][r];
                float cand = __fadd_rn(__fsub_rn(x2p, __fmul_rn(2.0f, s)), c2v[ki]);
                int   kidx = wid * 128 + ki * 16 + l15;
                if (cand < v1 || (cand == v1 && kidx < k1)) { v2 = v1; v1 = cand; k1 = kidx; }
                else if (cand < v2) v2 = cand;
            }
            #pragma unroll
            for (int off = 1; off < 16; off <<= 1) {
                float ov1 = __shfl_xor(v1, off, 64);
                int   ok1 = __shfl_xor(k1, off, 64);
                float ov2 = __shfl_xor(v2, off, 64);
                if (ov1 < v1 || (ov1 == v1 && ok1 < k1)) { v2 = fminf(v1, ov2); v1 = ov1; k1 = ok1; }
                else v2 = fminf(v2, ov1);
            }
            if (l15 == 0) { rv1s[wid][p] = v1; rv2s[wid][p] = v2; rk1s[wid][p] = k1; }
        }
    }
    __syncthreads();
    if (tid < 64) {
        float v1 = rv1s[0][tid], v2 = rv2s[0][tid];
        int   k1 = rk1s[0][tid];
        #pragma unroll
        for (int w = 1; w < 4; ++w) {
            float ov1 = rv1s[w][tid], ov2 = rv2s[w][tid];
            int   ok1 = rk1s[w][tid];
            if (ov1 < v1 || (ov1 == v1 && ok1 < k1)) { v2 = fminf(v1, ov2); v1 = ov1; k1 = ok1; }
            else v2 = fminf(v2, ov1);
        }
        int g = b * NN + m0 + tid;
        labels[g] = k1;
        if (v2 - v1 < TAU) {
            int pos = atomicAdd(flagslot, 1);
            flaglist[pos] = g;
        }
    }
}

// ---------- exact (f64) re-rank of flagged points + dirty-array zero -------
__global__ __launch_bounds__(256) void refine_k(const float* __restrict__ x,
                                                const float* __restrict__ centers,
                                                const int* __restrict__ flagslot,
                                                const int* __restrict__ flaglist,
                                                int* __restrict__ labels,
                                                int* __restrict__ dirty) {
    __shared__ float  xsr[DD];
    __shared__ double sv[256];
    __shared__ int    si[256];
    const int t = threadIdx.x;
    if (t < 2) dirty[blockIdx.x * 2 + t] = 0;      // grid 1024 x 2 = 2048
    const int cnt = flagslot[0];
    for (int idx = blockIdx.x; idx < cnt; idx += gridDim.x) {
        const int g = flaglist[idx];
        const int b = g >> 13;
        __syncthreads();
        xsr[t] = x[(size_t)g * DD + t];
        __syncthreads();
        const float* cbase = centers + (size_t)b * KK * DD;
        double bestv = 1e300; int bestk = 0x7fffffff;
        #pragma unroll
        for (int h = 0; h < 2; ++h) {
            int k = t + h * 256;
            const float* cr = cbase + (size_t)k * DD;
            double a0 = 0, a1 = 0, a2 = 0, a3 = 0;
            for (int d = 0; d < DD; d += 4) {
                float4 cv = *(const float4*)(cr + d);
                double f0 = (double)xsr[d + 0] - (double)cv.x;
                double f1 = (double)xsr[d + 1] - (double)cv.y;
                double f2 = (double)xsr[d + 2] - (double)cv.z;
                double f3 = (double)xsr[d + 3] - (double)cv.w;
                a0 += f0 * f0; a1 += f1 * f1; a2 += f2 * f2; a3 += f3 * f3;
            }
            double dist = (a0 + a1) + (a2 + a3);
            if (dist < bestv || (dist == bestv && k < bestk)) { bestv = dist; bestk = k; }
        }
        sv[t] = bestv; si[t] = bestk;
        __syncthreads();
        for (int s = 128; s > 0; s >>= 1) {
            if (t < s) {
                if (sv[t + s] < sv[t] || (sv[t + s] == sv[t] && si[t + s] < si[t])) {
                    sv[t] = sv[t + s]; si[t] = si[t + s];
                }
            }
            __syncthreads();
        }
        if (t == 0) labels[g] = si[0];
    }
}

// ------- dirty detection: compare labels vs prev, mark both clusters -------
__global__ __launch_bounds__(256) void dirty_k(const int* __restrict__ labels,
                                               int* __restrict__ labels_prev,
                                               int* __restrict__ dirty) {
    int n = blockIdx.x * 256 + threadIdx.x;   // 0..BB*NN-1
    int b = n >> 13;
    int l  = labels[n];
    int lp = labels_prev[n];
    if (l != lp) {
        dirty[b * KK + l] = 1;                // idempotent stores
        if (lp >= 0 && lp < KK) dirty[b * KK + lp] = 1;
        labels_prev[n] = l;
    }
}

// ------- centers update: direct label scan (no sort), wave-ordered sums ----
// Block per cluster (16 waves); wave w scans points [w*512,(w+1)*512) in
// n-ascending order, accumulates member rows; partials combined in fixed
// wave order. Skips clean clusters (dirty flag).
__global__ __launch_bounds__(1024) void centers_update_k(const float* __restrict__ x,
                                                         const int* __restrict__ labels,
                                                         float* __restrict__ centers,
                                                         f16* __restrict__ chh,
                                                         float* __restrict__ c2,
                                                         const int* __restrict__ dirty) {
    __shared__ float part[16][DD];
    __shared__ int   cnts[16];
    __shared__ float sq[256];
    const int bk   = blockIdx.x;
    const int b    = bk >> 9;
    const int k    = bk & 511;
    const int tid  = threadIdx.x;
    const int w    = tid >> 6;        // 0..15
    const int lane = tid & 63;
    if (!dirty[bk]) return;           // member list unchanged -> center identical
    const int* lb = labels + b * NN;
    const float* xb = x + (size_t)b * NN * DD;
    float4 acc = {0.f, 0.f, 0.f, 0.f};
    int cnt = 0;
    #pragma unroll 4
    for (int n = w * 512; n < (w + 1) * 512; ++n) {
        if (lb[n] == k) {
            float4 v = *(const float4*)(xb + (size_t)n * DD + lane * 4);
            acc.x = __fadd_rn(acc.x, v.x);
            acc.y = __fadd_rn(acc.y, v.y);
            acc.z = __fadd_rn(acc.z, v.z);
            acc.w = __fadd_rn(acc.w, v.w);
            ++cnt;
        }
    }
    *(float4*)&part[w][lane * 4] = acc;
    if (lane == 0) cnts[w] = cnt;
    __syncthreads();
    // total count (uniform)
    __shared__ int total;
    if (tid == 0) {
        int s = 0;
        #pragma unroll
        for (int w2 = 0; w2 < 16; ++w2) s += cnts[w2];
        total = s;
    }
    __syncthreads();
    const int tc = total;
    if (tc == 0) return;              // centers/mirror/c2 stay valid
    float val = 0.f;
    if (tid < DD) {
        float s = 0.f;
        #pragma unroll
        for (int w2 = 0; w2 < 16; ++w2) s = __fadd_rn(s, part[w2][tid]);
        val = s / (float)tc;
        size_t idx = (size_t)bk * DD + tid;
        centers[idx] = val;
        chh[idx] = (f16)val;
    }
    if (tid < 256) sq[tid] = val * val;
    __syncthreads();
    for (int s = 128; s > 0; s >>= 1) {
        if (tid < s) sq[tid] += sq[tid + s];
        __syncthreads();
    }
    if (tid == 0) c2[bk] = sq[0];
}

// ---------------- fused output: labels (as float) + centers ----------------
__global__ __launch_bounds__(256) void out_k(const int* __restrict__ labels,
                                             const float* __restrict__ centers,
                                             float* __restrict__ out) {
    size_t i = (size_t)blockIdx.x * 256 + threadIdx.x;
    if (i < (size_t)BB * NN) out[i] = (float)labels[i];
    else                     out[i] = centers[i - (size_t)BB * NN];
}

extern "C" void kernel_launch(void* const* d_in, const int* in_sizes, int n_in,
                              void* d_out, int out_size, void* d_ws, size_t ws_size,
                              hipStream_t stream) {
    const float* x = (const float*)d_in[0];
    float* out = (float*)d_out;
    float* ws  = (float*)d_ws;

    // ws layout
    float* centers  = ws;                                   // BB*KK*DD f32
    float* c2       = centers + (size_t)BB * KK * DD;       // BB*KK
    float* x2       = c2 + BB * KK;                         // BB*NN
    int*   labels   = (int*)(x2 + BB * NN);                 // BB*NN
    int*   flagcnt  = labels + BB * NN;                     // 64 (one slot per pass)
    int*   flaglist = flagcnt + 64;                         // BB*NN
    int*   labels_prev = flaglist + BB * NN;                // BB*NN
    int*   dirty    = labels_prev + BB * NN;                // BB*KK
    f16*   chh      = (f16*)(dirty + BB * KK);              // BB*KK*DD f16
    f16*   xh16     = chh + (size_t)BB * KK * DD;           // BB*NN*DD f16
    f16*   xl16     = xh16 + (size_t)BB * NN * DD;          // BB*NN*DD f16

    hipMemsetAsync(flagcnt, 0, 64 * sizeof(int), stream);
    hipMemsetAsync(labels_prev, 0xFF, (size_t)BB * NN * sizeof(int), stream);

    init_centers_k<<<BB * KK, 256, 0, stream>>>(x, centers, chh, c2);
    xsplit_k<<<(int)((size_t)BB * NN * DD / 8 / 256), 256, 0, stream>>>(x, xh16, xl16);
    rowsumsq_k<<<(BB * NN + 255) / 256, 256, 0, stream>>>(x, x2, BB * NN);

    for (int it = 0; it < NITERS; ++it) {
        assign_k<<<BB * (NN / 64), 256, 0, stream>>>(xh16, xl16, chh, x2, c2,
                                                     labels, flagcnt + it, flaglist);
        refine_k<<<1024, 256, 0, stream>>>(x, centers, flagcnt + it, flaglist,
                                           labels, dirty);
        dirty_k<<<BB * NN / 256, 256, 0, stream>>>(labels, labels_prev, dirty);
        centers_update_k<<<BB * KK, 1024, 0, stream>>>(x, labels, centers, chh, c2,
                                                       dirty);
    }

    assign_k<<<BB * (NN / 64), 256, 0, stream>>>(xh16, xl16, chh, x2, c2,
                                                 labels, flagcnt + NITERS, flaglist);
    refine_k<<<1024, 256, 0, stream>>>(x, centers, flagcnt + NITERS, flaglist,
                                       labels, dirty);

    out_k<<<(int)(((size_t)BB * NN + (size_t)BB * KK * DD + 255) / 256), 256, 0, stream>>>(
        labels, centers, out);
}

// Round 24
// 930.550 us; speedup vs baseline: 1.9478x; 1.9478x over previous
//
#include <hip/hip_runtime.h>
#include <math.h>

#define BB 4
#define NN 8192
#define DD 256
#define KK 512
#define NITERS 10

#define TAU 0.06f     // 2-term margin below which we re-rank in f64
#define NCH 128       // 64-point chunks per batch (NN/64)

typedef _Float16 f16;
typedef f16   f16x8 __attribute__((ext_vector_type(8)));
typedef float f32x4 __attribute__((ext_vector_type(4)));

// ---------------- init: centers0 = x[:, :K, :]  (f32 + f16 hi + c2) --------
__global__ __launch_bounds__(256) void init_centers_k(const float* __restrict__ x,
                                                      float* __restrict__ centers,
                                                      f16* __restrict__ chh,
                                                      float* __restrict__ c2) {
    __shared__ float sq[256];
    int bk = blockIdx.x;
    int b  = bk >> 9;
    int k  = bk & 511;
    int t  = threadIdx.x;
    size_t idx = (size_t)bk * DD + t;
    float v = x[((size_t)b * NN + k) * DD + t];
    centers[idx] = v;
    chh[idx] = (f16)v;
    sq[t] = v * v;
    __syncthreads();
    for (int s = 128; s > 0; s >>= 1) {
        if (t < s) sq[t] += sq[t + s];
        __syncthreads();
    }
    if (t == 0) c2[bk] = sq[0];
}

// ---------------- row sum of squares for x (once per call) -----------------
__global__ __launch_bounds__(256) void rowsumsq_k(const float* __restrict__ rows,
                                                  float* __restrict__ out, int nrows) {
    int r = blockIdx.x * 256 + threadIdx.x;
    if (r >= nrows) return;
    const float* p = rows + (size_t)r * DD;
    float total = 0.f;
    #pragma unroll
    for (int h = 0; h < 2; ++h) {
        float a[8];
        #pragma unroll
        for (int j = 0; j < 8; ++j) a[j] = 0.f;
        for (int i = 0; i < 128; i += 8) {
            #pragma unroll
            for (int j = 0; j < 8; ++j) {
                float v  = p[h * 128 + i + j];
                float sq = __fmul_rn(v, v);
                a[j] = __fadd_rn(a[j], sq);
            }
        }
        float s = __fadd_rn(__fadd_rn(__fadd_rn(a[0], a[1]), __fadd_rn(a[2], a[3])),
                            __fadd_rn(__fadd_rn(a[4], a[5]), __fadd_rn(a[6], a[7])));
        total = __fadd_rn(total, s);
    }
    out[r] = total;
}

// ---------------- 2-term split-f16 MFMA distance (R17 shape) ---------------
__global__ __launch_bounds__(256, 2) void assign_k(
    const float* __restrict__ x,
    const f16* __restrict__ chh,
    const float* __restrict__ x2g, const float* __restrict__ c2g,
    int* __restrict__ labels, int* __restrict__ flagslot, int* __restrict__ flaglist)
{
    __shared__ f16 xlh[64 * 256];
    __shared__ f16 xll[64 * 256];
    __shared__ float rv1s[4][64];
    __shared__ float rv2s[4][64];
    __shared__ int   rk1s[4][64];

    const int tid  = threadIdx.x;
    const int wid  = tid >> 6;
    const int lane = tid & 63;
    const int l15  = lane & 15;
    const int lg   = lane >> 4;          // 0..3
    const int b    = blockIdx.x >> 7;    // 128 blocks per batch
    const int m0   = (blockIdx.x & 127) * 64;

    const float* xb = x + (size_t)(b * NN + m0) * DD;

    // stage x tile (64 x 256) -> f16 hi/lo, swizzled granules
    #pragma unroll
    for (int i = 0; i < 8; ++i) {
        int lin = tid + i * 256;          // 0..2047
        int row = lin >> 5, g = lin & 31;
        const float* p = xb + row * DD + g * 8;
        float4 a  = *(const float4*)p;
        float4 bq = *(const float4*)(p + 4);
        float vf[8] = {a.x, a.y, a.z, a.w, bq.x, bq.y, bq.z, bq.w};
        f16x8 hv, lv;
        #pragma unroll
        for (int j = 0; j < 8; ++j) {
            f16 h = (f16)vf[j];
            hv[j] = h;
            lv[j] = (f16)(vf[j] - (float)h);
        }
        int si = row * 256 + ((g ^ (row & 7)) << 3);
        *(f16x8*)&xlh[si] = hv;
        *(f16x8*)&xll[si] = lv;
    }
    __syncthreads();

    const f16* bhb = chh + ((size_t)b * KK + wid * 128) * DD;

    f32x4 acc[4][8];
    #pragma unroll
    for (int mi = 0; mi < 4; ++mi)
        #pragma unroll
        for (int ki = 0; ki < 8; ++ki)
            acc[mi][ki] = (f32x4){0.f, 0.f, 0.f, 0.f};

    #pragma unroll
    for (int s = 0; s < 8; ++s) {
        const int d0 = s * 32;
        f16x8 bh[8];
        #pragma unroll
        for (int ki = 0; ki < 8; ++ki) {
            size_t off = (size_t)(ki * 16 + l15) * DD + d0 + lg * 8;
            bh[ki] = *(const f16x8*)(bhb + off);
        }
        f16x8 ah[4], al[4];
        #pragma unroll
        for (int mi = 0; mi < 4; ++mi) {
            int row = mi * 16 + l15;
            int g   = (d0 >> 3) + lg;
            int si  = row * 256 + ((g ^ (row & 7)) << 3);
            ah[mi] = *(const f16x8*)&xlh[si];
            al[mi] = *(const f16x8*)&xll[si];
        }
        #pragma unroll
        for (int ki = 0; ki < 8; ++ki) {
            #pragma unroll
            for (int mi = 0; mi < 4; ++mi) {
                acc[mi][ki] = __builtin_amdgcn_mfma_f32_16x16x32_f16(ah[mi], bh[ki], acc[mi][ki], 0, 0, 0);
                acc[mi][ki] = __builtin_amdgcn_mfma_f32_16x16x32_f16(al[mi], bh[ki], acc[mi][ki], 0, 0, 0);
            }
        }
    }

    // epilogue: candidates + top-2 (point = mi*16+lg*4+r, col = wid*128+ki*16+l15)
    float c2v[8];
    #pragma unroll
    for (int ki = 0; ki < 8; ++ki)
        c2v[ki] = c2g[b * KK + wid * 128 + ki * 16 + l15];

    #pragma unroll
    for (int mi = 0; mi < 4; ++mi) {
        #pragma unroll
        for (int r = 0; r < 4; ++r) {
            int p = mi * 16 + lg * 4 + r;
            float x2p = x2g[b * NN + m0 + p];
            float v1 = __builtin_inff(), v2 = __builtin_inff();
            int   k1 = 0x7fffffff;
            #pragma unroll
            for (int ki = 0; ki < 8; ++ki) {
                float s    = acc[mi][ki][r];
                float cand = __fadd_rn(__fsub_rn(x2p, __fmul_rn(2.0f, s)), c2v[ki]);
                int   kidx = wid * 128 + ki * 16 + l15;
                if (cand < v1 || (cand == v1 && kidx < k1)) { v2 = v1; v1 = cand; k1 = kidx; }
                else if (cand < v2) v2 = cand;
            }
            #pragma unroll
            for (int off = 1; off < 16; off <<= 1) {
                float ov1 = __shfl_xor(v1, off, 64);
                int   ok1 = __shfl_xor(k1, off, 64);
                float ov2 = __shfl_xor(v2, off, 64);
                if (ov1 < v1 || (ov1 == v1 && ok1 < k1)) { v2 = fminf(v1, ov2); v1 = ov1; k1 = ok1; }
                else v2 = fminf(v2, ov1);
            }
            if (l15 == 0) { rv1s[wid][p] = v1; rv2s[wid][p] = v2; rk1s[wid][p] = k1; }
        }
    }
    __syncthreads();
    if (tid < 64) {
        float v1 = rv1s[0][tid], v2 = rv2s[0][tid];
        int   k1 = rk1s[0][tid];
        #pragma unroll
        for (int w = 1; w < 4; ++w) {
            float ov1 = rv1s[w][tid], ov2 = rv2s[w][tid];
            int   ok1 = rk1s[w][tid];
            if (ov1 < v1 || (ov1 == v1 && ok1 < k1)) { v2 = fminf(v1, ov2); v1 = ov1; k1 = ok1; }
            else v2 = fminf(v2, ov1);
        }
        int g = b * NN + m0 + tid;
        labels[g] = k1;
        if (v2 - v1 < TAU) {
            int pos = atomicAdd(flagslot, 1);
            flaglist[pos] = g;
        }
    }
}

// ---------- exact (f64) re-rank of flagged points + dirty-array zero -------
__global__ __launch_bounds__(256) void refine_k(const float* __restrict__ x,
                                                const float* __restrict__ centers,
                                                const int* __restrict__ flagslot,
                                                const int* __restrict__ flaglist,
                                                int* __restrict__ labels,
                                                int* __restrict__ dirty) {
    __shared__ float  xsr[DD];
    __shared__ double sv[256];
    __shared__ int    si[256];
    const int t = threadIdx.x;
    if (t < 2) dirty[blockIdx.x * 2 + t] = 0;      // grid 1024 x 2 = 2048
    const int cnt = flagslot[0];
    for (int idx = blockIdx.x; idx < cnt; idx += gridDim.x) {
        const int g = flaglist[idx];
        const int b = g >> 13;
        __syncthreads();
        xsr[t] = x[(size_t)g * DD + t];
        __syncthreads();
        const float* cbase = centers + (size_t)b * KK * DD;
        double bestv = 1e300; int bestk = 0x7fffffff;
        #pragma unroll
        for (int h = 0; h < 2; ++h) {
            int k = t + h * 256;
            const float* cr = cbase + (size_t)k * DD;
            double a0 = 0, a1 = 0, a2 = 0, a3 = 0;
            for (int d = 0; d < DD; d += 4) {
                float4 cv = *(const float4*)(cr + d);
                double f0 = (double)xsr[d + 0] - (double)cv.x;
                double f1 = (double)xsr[d + 1] - (double)cv.y;
                double f2 = (double)xsr[d + 2] - (double)cv.z;
                double f3 = (double)xsr[d + 3] - (double)cv.w;
                a0 += f0 * f0; a1 += f1 * f1; a2 += f2 * f2; a3 += f3 * f3;
            }
            double dist = (a0 + a1) + (a2 + a3);
            if (dist < bestv || (dist == bestv && k < bestk)) { bestv = dist; bestk = k; }
        }
        sv[t] = bestv; si[t] = bestk;
        __syncthreads();
        for (int s = 128; s > 0; s >>= 1) {
            if (t < s) {
                if (sv[t + s] < sv[t] || (sv[t + s] == sv[t] && si[t + s] < si[t])) {
                    sv[t] = sv[t + s]; si[t] = si[t + s];
                }
            }
            __syncthreads();
        }
        if (t == 0) labels[g] = si[0];
    }
}

// ------- chunk histogram + dirty-cluster detection -------------------------
__global__ __launch_bounds__(64) void chunk_hist_k(const int* __restrict__ labels,
                                                   int* __restrict__ labels_prev,
                                                   int* __restrict__ dirty,
                                                   int* __restrict__ chunkhist) {
    __shared__ int h[KK];
    const int bc = blockIdx.x;        // b*NCH + c
    const int b  = bc >> 7;
    const int c  = bc & (NCH - 1);
    const int t  = threadIdx.x;
    for (int k = t; k < KK; k += 64) h[k] = 0;
    __syncthreads();
    int n  = b * NN + c * 64 + t;
    int l  = labels[n];
    int lp = labels_prev[n];
    atomicAdd(&h[l], 1);
    if (l != lp) {
        dirty[b * KK + l] = 1;
        if (lp >= 0 && lp < KK) dirty[b * KK + lp] = 1;
        labels_prev[n] = l;
    }
    __syncthreads();
    int* ch = chunkhist + (size_t)bc * KK;
    for (int k = t; k < KK; k += 64) ch[k] = h[k];
}

// fused: column prefix over 128 chunks (batched-16) + block scan for offsets
__global__ __launch_bounds__(512) void scan_k(int* __restrict__ chunkhist,
                                              int* __restrict__ counts,
                                              int* __restrict__ offsets) {
    __shared__ int s[KK];
    const int b = blockIdx.x;
    const int k = threadIdx.x;
    int* ch = chunkhist + (size_t)b * NCH * KK;
    int run = 0;
    for (int c0 = 0; c0 < NCH; c0 += 16) {
        int v[16];
        #pragma unroll
        for (int j = 0; j < 16; ++j) v[j] = ch[(size_t)(c0 + j) * KK + k];
        #pragma unroll
        for (int j = 0; j < 16; ++j) {
            ch[(size_t)(c0 + j) * KK + k] = run;
            run += v[j];
        }
    }
    counts[b * KK + k] = run;
    s[k] = run;
    __syncthreads();
    for (int off = 1; off < KK; off <<= 1) {
        int v = (k >= off) ? s[k - off] : 0;
        __syncthreads();
        s[k] += v;
        __syncthreads();
    }
    offsets[b * KK + k] = s[k] - run;   // exclusive
}

__global__ __launch_bounds__(64) void scatter_k(const int* __restrict__ labels,
                                                const int* __restrict__ chunkhist,
                                                const int* __restrict__ offsets,
                                                int* __restrict__ idxlist) {
    const int bc = blockIdx.x;
    const int b  = bc >> 7;
    const int c  = bc & (NCH - 1);
    const int t  = threadIdx.x;
    const int n  = c * 64 + t;
    const int l  = labels[b * NN + n];
    int rank = 0;
    for (int j = 0; j < 64; ++j) {
        int lj = __shfl(l, j, 64);
        rank += (lj == l && j < t) ? 1 : 0;
    }
    int base = offsets[b * KK + l] + chunkhist[(size_t)bc * KK + l];
    idxlist[b * NN + base + rank] = n;
}

// ------- centers update: skips clean clusters (bit-identical result) -------
__global__ __launch_bounds__(1024) void centers_update_k(const float* __restrict__ x,
                                                         float* __restrict__ centers,
                                                         f16* __restrict__ chh,
                                                         float* __restrict__ c2,
                                                         const int* __restrict__ counts,
                                                         const int* __restrict__ offsets,
                                                         const int* __restrict__ idxlist,
                                                         const int* __restrict__ dirty) {
    __shared__ float part[16][DD];
    __shared__ float sq[256];
    const int bk   = blockIdx.x;
    const int b    = bk >> 9;
    const int tid  = threadIdx.x;
    const int w    = tid >> 6;        // 0..15
    const int lane = tid & 63;
    if (!dirty[bk]) return;           // member list unchanged -> center identical
    const int cnt = counts[bk];
    if (cnt == 0) return;             // centers/mirror/c2 stay valid
    const int* il = idxlist + b * NN + offsets[bk];
    const float* xb = x + (size_t)b * NN * DD;
    float4 acc = {0.f, 0.f, 0.f, 0.f};
    #pragma unroll 8
    for (int j = w; j < cnt; j += 16) {
        int n = il[j];
        float4 v = *(const float4*)(xb + (size_t)n * DD + lane * 4);
        acc.x = __fadd_rn(acc.x, v.x);
        acc.y = __fadd_rn(acc.y, v.y);
        acc.z = __fadd_rn(acc.z, v.z);
        acc.w = __fadd_rn(acc.w, v.w);
    }
    *(float4*)&part[w][lane * 4] = acc;
    __syncthreads();
    float val = 0.f;
    if (tid < DD) {
        float s = 0.f;
        #pragma unroll
        for (int w2 = 0; w2 < 16; ++w2) s = __fadd_rn(s, part[w2][tid]);
        val = s / (float)cnt;
        size_t idx = (size_t)bk * DD + tid;
        centers[idx] = val;
        chh[idx] = (f16)val;
    }
    if (tid < 256) sq[tid] = val * val;
    __syncthreads();
    for (int s = 128; s > 0; s >>= 1) {
        if (tid < s) sq[tid] += sq[tid + s];
        __syncthreads();
    }
    if (tid == 0) c2[bk] = sq[0];
}

// ---------------- fused output: labels (as float) + centers ----------------
__global__ __launch_bounds__(256) void out_k(const int* __restrict__ labels,
                                             const float* __restrict__ centers,
                                             float* __restrict__ out) {
    size_t i = (size_t)blockIdx.x * 256 + threadIdx.x;
    if (i < (size_t)BB * NN) out[i] = (float)labels[i];
    else                     out[i] = centers[i - (size_t)BB * NN];
}

extern "C" void kernel_launch(void* const* d_in, const int* in_sizes, int n_in,
                              void* d_out, int out_size, void* d_ws, size_t ws_size,
                              hipStream_t stream) {
    const float* x = (const float*)d_in[0];
    float* out = (float*)d_out;
    float* ws  = (float*)d_ws;

    // ws layout
    float* centers  = ws;                                   // BB*KK*DD f32
    float* c2       = centers + (size_t)BB * KK * DD;       // BB*KK
    float* x2       = c2 + BB * KK;                         // BB*NN
    int*   labels   = (int*)(x2 + BB * NN);                 // BB*NN
    int*   flagcnt  = labels + BB * NN;                     // 64 (one slot per pass)
    int*   flaglist = flagcnt + 64;                         // BB*NN
    int*   counts   = flaglist + BB * NN;                   // BB*KK
    int*   offsets  = counts + BB * KK;                     // BB*KK
    int*   idxlist  = offsets + BB * KK;                    // BB*NN
    int*   chunkhist= idxlist + BB * NN;                    // BB*NCH*KK
    f16*   chh      = (f16*)(chunkhist + (size_t)BB * NCH * KK);  // BB*KK*DD f16
    int*   labels_prev = (int*)(chh + (size_t)BB * KK * DD);      // BB*NN
    int*   dirty    = labels_prev + BB * NN;                // BB*KK

    hipMemsetAsync(flagcnt, 0, 64 * sizeof(int), stream);
    hipMemsetAsync(labels_prev, 0xFF, (size_t)BB * NN * sizeof(int), stream);

    init_centers_k<<<BB * KK, 256, 0, stream>>>(x, centers, chh, c2);
    rowsumsq_k<<<(BB * NN + 255) / 256, 256, 0, stream>>>(x, x2, BB * NN);

    for (int it = 0; it < NITERS; ++it) {
        assign_k<<<BB * (NN / 64), 256, 0, stream>>>(x, chh, x2, c2,
                                                     labels, flagcnt + it, flaglist);
        refine_k<<<1024, 256, 0, stream>>>(x, centers, flagcnt + it, flaglist,
                                           labels, dirty);
        chunk_hist_k<<<BB * NCH, 64, 0, stream>>>(labels, labels_prev, dirty, chunkhist);
        scan_k<<<BB, 512, 0, stream>>>(chunkhist, counts, offsets);
        scatter_k<<<BB * NCH, 64, 0, stream>>>(labels, chunkhist, offsets, idxlist);
        centers_update_k<<<BB * KK, 1024, 0, stream>>>(x, centers, chh, c2,
                                                       counts, offsets, idxlist, dirty);
    }

    assign_k<<<BB * (NN / 64), 256, 0, stream>>>(x, chh, x2, c2,
                                                 labels, flagcnt + NITERS, flaglist);
    refine_k<<<1024, 256, 0, stream>>>(x, centers, flagcnt + NITERS, flaglist,
                                       labels, dirty);

    out_k<<<(int)(((size_t)BB * NN + (size_t)BB * KK * DD + 255) / 256), 256, 0, stream>>>(
        labels, centers, out);
}